// Round 14
// baseline (178.351 us; speedup 1.0000x reference)
//
#include <hip/hip_runtime.h>

#define D 1024
#define T 2048
#define BATCH 2
#define NR 4096
#define NH 16
#define HID 512

typedef unsigned short u16;
typedef unsigned int u32;
typedef unsigned long long u64;
typedef float f32x4 __attribute__((ext_vector_type(4)));
typedef float f32x16 __attribute__((ext_vector_type(16)));
typedef __bf16 bf16x8 __attribute__((ext_vector_type(8)));

// native RNE f32->bf16 (hardware v_cvt)
__device__ __forceinline__ u16 f2bf(float f) {
    union { __bf16 h; u16 u; } c; c.h = (__bf16)f; return c.u;
}
// bf16 bits -> f32 (exact)
__device__ __forceinline__ float bf2f(u16 u) {
    union { u32 u; float f; } c; c.u = ((u32)u) << 16; return c.f;
}

// pack two f32 -> 2xbf16 in one u32 (low = a, high = b). No builtin on gfx950 (m240).
__device__ __forceinline__ u32 cvtpk(float a, float b) {
    u32 r;
    asm("v_cvt_pk_bf16_f32 %0, %1, %2" : "=v"(r) : "v"(a), "v"(b));
    return r;
}

// v_permlane32_swap_b32: x[32..63] <-> y[0..31].
__device__ __forceinline__ void plswap(u32& x, u32& y) {
    asm volatile("v_permlane32_swap_b32 %0, %1" : "+v"(x), "+v"(y));
}

__device__ __forceinline__ float fmax3(float a, float b, float c) {
    float r; asm("v_max3_f32 %0, %1, %2, %3" : "=v"(r) : "v"(a), "v"(b), "v"(c)); return r;
}

// max over an f32x16 with ILP tree (8 ops)
__device__ __forceinline__ float vmax16(const f32x16& v) {
    float c0 = fmax3(v[0], v[1], v[2]);
    float c1 = fmax3(v[3], v[4], v[5]);
    float c2 = fmax3(v[6], v[7], v[8]);
    float c3 = fmax3(v[9], v[10], v[11]);
    c0 = fmax3(c0, v[12], v[13]);
    c1 = fmax3(c1, v[14], v[15]);
    c0 = fmax3(c0, c1, c2);
    return fmaxf(c0, c3);
}

// async global->LDS, 16B per lane. LDS dest lane-linear; read-side XOR swizzle realized
// by pre-swizzling the GLOBAL source column (both-sides-or-neither).
__device__ __forceinline__ void gload16(const u16* g, u16* l) {
    __builtin_amdgcn_global_load_lds(
        (const __attribute__((address_space(1))) unsigned int*)g,
        (__attribute__((address_space(3))) unsigned int*)l,
        16, 0, 0);
}

// conflict-free slot swizzle for 8-slot (128B) rows read at 32-row stride
__device__ __forceinline__ int swz8(int row) {
    return (row & 7) ^ ((row >> 3) & 3);
}

// ---- fused prep: PE (blocks 0..4095) | wconv (4096..5119) | quantile MLP + scl (5120..5143) ----
__global__ __launch_bounds__(256) void k_prep(const float* __restrict__ x, u16* __restrict__ xpeb,
        const float* __restrict__ Wq, const float* __restrict__ Wk,
        const float* __restrict__ Wv, const float* __restrict__ Wo, u16* __restrict__ Wt,
        const float* __restrict__ qtl, const float* __restrict__ qimp,
        const float* __restrict__ w1q, const float* __restrict__ b1q, const float* __restrict__ w2q, const float* __restrict__ b2q,
        const float* __restrict__ w1k, const float* __restrict__ b1k, const float* __restrict__ w2k, const float* __restrict__ b2k,
        const float* __restrict__ w1v, const float* __restrict__ b1v, const float* __restrict__ w2v, const float* __restrict__ b2v,
        float* __restrict__ embeds, float* __restrict__ scl)
{
    int tid = threadIdx.x;
    if (blockIdx.x < 4096) {
        int idx = (blockIdx.x * 256 + tid) * 4;
        int d = idx & (D - 1);
        int t = (idx >> 10) & (T - 1);
        const float KL = -0.0089944731946f;  // -ln(10000)/1024
        float ft = (float)t;
        float dv0 = __expf((float)d * KL);
        float dv1 = __expf((float)(d + 2) * KL);
        float a0 = ft * dv0, a1 = ft * dv1;
        float4 xv = *reinterpret_cast<const float4*>(x + idx);
        ushort4 o;
        o.x = f2bf(xv.x + __sinf(a0));
        o.y = f2bf(xv.y + __cosf(a0));
        o.z = f2bf(xv.z + __sinf(a1));
        o.w = f2bf(xv.w + __cosf(a1));
        *reinterpret_cast<ushort4*>(xpeb + idx) = o;
        return;
    }
    if (blockIdx.x < 5120) {
        __shared__ float tile[64][65];
        int bi = blockIdx.x - 4096;
        int z = bi >> 8;
        const float* W = z == 0 ? Wq : z == 1 ? Wk : z == 2 ? Wv : Wo;
        u16* out = Wt + (size_t)z * D * D;
        int n0 = (bi & 15) * 64, k0 = ((bi >> 4) & 15) * 64;
        int r = tid >> 4;
        int c4 = (tid & 15) * 4;
        #pragma unroll
        for (int rr = 0; rr < 64; rr += 16) {
            float4 v = *reinterpret_cast<const float4*>(W + (size_t)(k0 + r + rr) * D + n0 + c4);
            tile[r + rr][c4 + 0] = v.x; tile[r + rr][c4 + 1] = v.y;
            tile[r + rr][c4 + 2] = v.z; tile[r + rr][c4 + 3] = v.w;
        }
        __syncthreads();
        #pragma unroll
        for (int rr = 0; rr < 64; rr += 16) {
            ushort4 o;
            o.x = f2bf(tile[c4 + 0][r + rr]);
            o.y = f2bf(tile[c4 + 1][r + rr]);
            o.z = f2bf(tile[c4 + 2][r + rr]);
            o.w = f2bf(tile[c4 + 3][r + rr]);
            *reinterpret_cast<ushort4*>(out + (size_t)(n0 + r + rr) * D + k0 + c4) = o;
        }
        return;
    }
    // quantile MLP: bi2 = dc(0..3) | wb(0..5)<<2 ; wb = which*2 + b
    __shared__ float h[HID];
    int bi2 = blockIdx.x - 5120;
    int dc = bi2 & 3, wb = bi2 >> 2;
    int which = wb >> 1, b = wb & 1;
    const float *w1, *b1, *w2, *b2;
    if (which == 0)      { w1 = w1q; b1 = b1q; w2 = w2q; b2 = b2q; }
    else if (which == 1) { w1 = w1k; b1 = b1k; w2 = w2k; b2 = b2k; }
    else                 { w1 = w1v; b1 = b1v; w2 = w2v; b2 = b2v; }
    float qv = qtl[b];
    h[tid] = fmaxf(qv * w1[tid] + b1[tid], 0.0f);
    h[tid + 256] = fmaxf(qv * w1[tid + 256] + b1[tid + 256], 0.0f);
    __syncthreads();
    int d = dc * 256 + tid;
    float acc = b2[d];
    for (int j = 0; j < HID; ++j) acc += h[j] * w2[(size_t)j * D + d];
    embeds[(size_t)wb * D + d] = acc;
    if (bi2 == 0 && tid < BATCH) {
        float mx = qimp[0];
        for (int i = 1; i < 100; ++i) mx = fmaxf(mx, qimp[i]);
        float q = qtl[tid];
        int idx = (int)(q * 100.0f);
        idx = idx < 0 ? 0 : (idx > 99 ? 99 : idx);
        float imp = qimp[idx];
        if (mx > 0.0f) imp /= mx;
        scl[tid] = 1.0f + imp;
    }
}

// ---------------- shared 128x128 GEMM core: 32x32x16 MFMA, single 32KB buffer ----------------
// A[m][k] row-major bf16, B = Wt[n][k] row-major bf16 (B^T layout). 4 waves, each owns a
// 64x64 output (2x2 of 32x32). C/D map: row=(reg&3)+8*(reg>>2)+4*(lane>>5), col=lane&31.
// Staging addresses are loop-invariant per thread; global pointers advance by 64/tile.
__device__ __forceinline__ void gemm128(const u16* __restrict__ Ag, const u16* __restrict__ Bg,
                                        int m0, int n0, f32x16 acc[2][2])
{
    __shared__ u16 As[128 * 64];
    __shared__ u16 Bs[128 * 64];
    const int tid = threadIdx.x;
    const int lane = tid & 63, wave = tid >> 6;
    const int wr = wave >> 1, wc = wave & 1;
    const int l31 = lane & 31, hb = lane >> 5;
    #pragma unroll
    for (int mi = 0; mi < 2; ++mi)
        #pragma unroll
        for (int ni = 0; ni < 2; ++ni)
            #pragma unroll
            for (int e = 0; e < 16; ++e) acc[mi][ni][e] = 0.0f;

    // precompute per-thread staging pointers (row, slot constant across tiles)
    const u16* ap[4]; const u16* bp[4]; u16* lda[4]; u16* ldb[4];
    #pragma unroll
    for (int c = 0; c < 4; ++c) {
        int ci = c * 256 + tid;
        int row = ci >> 3;
        int sl = (ci & 7) ^ swz8(row);
        ap[c] = Ag + (size_t)(m0 + row) * D + sl * 8;
        bp[c] = Bg + (size_t)(n0 + row) * D + sl * 8;
        lda[c] = As + (size_t)ci * 8;
        ldb[c] = Bs + (size_t)ci * 8;
    }

    for (int kt = 0; kt < 16; ++kt) {
        __syncthreads();   // prev tile fully consumed by all waves
        #pragma unroll
        for (int c = 0; c < 4; ++c) {
            gload16(ap[c], lda[c]);
            gload16(bp[c], ldb[c]);
            ap[c] += 64; bp[c] += 64;
        }
        __syncthreads();   // drains vmcnt(0): staged data visible to all
        #pragma unroll
        for (int ks = 0; ks < 4; ++ks) {
            bf16x8 af[2], bfr[2];
            #pragma unroll
            for (int mi = 0; mi < 2; ++mi) {
                int ra = wr * 64 + mi * 32 + l31;
                int sa = (2 * ks + hb) ^ swz8(ra);
                af[mi] = *reinterpret_cast<const bf16x8*>((const char*)As + ra * 128 + sa * 16);
                int rb = wc * 64 + mi * 32 + l31;
                int sb = (2 * ks + hb) ^ swz8(rb);
                bfr[mi] = *reinterpret_cast<const bf16x8*>((const char*)Bs + rb * 128 + sb * 16);
            }
            #pragma unroll
            for (int mi = 0; mi < 2; ++mi)
                #pragma unroll
                for (int ni = 0; ni < 2; ++ni)
                    acc[mi][ni] = __builtin_amdgcn_mfma_f32_32x32x16_bf16(af[mi], bfr[ni], acc[mi][ni], 0, 0, 0);
        }
    }
}

// ---------------- Q/K/V projections (Q pre-scaled by scl[b]*log2(e)/sqrt(dk)) ----------------
__global__ __launch_bounds__(256, 2)
void k_qkv(const u16* __restrict__ A, const u16* __restrict__ Wt,
           const float* __restrict__ bq, const float* __restrict__ bk, const float* __restrict__ bv,
           const float* __restrict__ embeds, const float* __restrict__ scl,
           u16* __restrict__ Qo, u16* __restrict__ Ko, u16* __restrict__ Vt)
{
    int which = blockIdx.z;
    const u16* Bg = Wt + (size_t)which * D * D;
    const float* bias = which == 0 ? bq : which == 1 ? bk : bv;
    const float* emb = embeds + which * (BATCH * D);
    int m0 = blockIdx.x * 128, n0 = blockIdx.y * 128;
    f32x16 acc[2][2];
    gemm128(A, Bg, m0, n0, acc);
    int lane = threadIdx.x & 63, wave = threadIdx.x >> 6;
    int wr = wave >> 1, wc = wave & 1;
    int l31 = lane & 31, hb = lane >> 5;
    if (which < 2) {
        u16* Out = which == 0 ? Qo : Ko;
        float sc0 = 1.0f, sc1 = 1.0f;
        if (which == 0) {
            sc0 = scl[0] * 0.125f * 1.44269504f;   // fold 1/sqrt(dk) * temp-scale * log2(e)
            sc1 = scl[1] * 0.125f * 1.44269504f;
        }
        #pragma unroll
        for (int ni = 0; ni < 2; ++ni) {
            int c = n0 + wc * 64 + ni * 32 + l31;
            float add0 = bias[c] + emb[c];
            float add1 = bias[c] + emb[D + c];
            #pragma unroll
            for (int mi = 0; mi < 2; ++mi) {
                #pragma unroll
                for (int reg = 0; reg < 16; ++reg) {
                    int r = m0 + wr * 64 + mi * 32 + (reg & 3) + 8 * (reg >> 2) + 4 * hb;
                    float v = (r >> 11) ? (acc[mi][ni][reg] + add1) * sc1
                                        : (acc[mi][ni][reg] + add0) * sc0;
                    Out[(size_t)r * D + c] = f2bf(v);
                }
            }
        }
    } else {
        // V stored transposed per-head: Vt[((b*NH + h)*64 + cc)][t]; reg&3 axis = 4 consecutive t
        #pragma unroll
        for (int ni = 0; ni < 2; ++ni) {
            int c = n0 + wc * 64 + ni * 32 + l31;
            int hh = c >> 6, cc = c & 63;
            float add0 = bias[c] + emb[c];
            float add1 = bias[c] + emb[D + c];
            #pragma unroll
            for (int mi = 0; mi < 2; ++mi) {
                #pragma unroll
                for (int g2 = 0; g2 < 4; ++g2) {
                    int r = m0 + wr * 64 + mi * 32 + 8 * g2 + 4 * hb;
                    int bb = r >> 11;
                    int t = r & (T - 1);
                    float add = bb ? add1 : add0;
                    ushort4 o;
                    o.x = f2bf(acc[mi][ni][4 * g2 + 0] + add);
                    o.y = f2bf(acc[mi][ni][4 * g2 + 1] + add);
                    o.z = f2bf(acc[mi][ni][4 * g2 + 2] + add);
                    o.w = f2bf(acc[mi][ni][4 * g2 + 3] + add);
                    *reinterpret_cast<ushort4*>(Vt + ((size_t)((bb * NH + hh) * 64 + cc)) * T + t) = o;
                }
            }
        }
    }
}

// ---------------- flash attention: split-KV, 8 waves (2 halves x 4 q-waves), KVBLK=64 ----------------
// R9 structure (best measured, 68.3us): LDS-staged K/V, stage-ahead dbuf, swz8 swizzle,
// 32x32x16 MFMA, swapped QK^T, in-register P via cvt_pk + permlane32_swap, split-KV LDS merge.
// Staging addresses hoisted to incremental pointers (row/slot loop-invariant).
__global__ __launch_bounds__(512, 4)
void k_attn(const u16* __restrict__ Q, const u16* __restrict__ K, const u16* __restrict__ Vt,
            u16* __restrict__ AO)
{
    __shared__ u16 Ks[2][2][64 * 64];   // [half][dbuf][t=64][d=64], 8x16B slots/row
    __shared__ u16 Vs[2][2][64 * 64];   // [half][dbuf][d=64][t=64], 8x16B slots/row
    int bh = blockIdx.x;
    int b = bh >> 4, hh = bh & 15;
    int q0 = blockIdx.y * 128;
    int tid = threadIdx.x;
    int lane = tid & 63, w = tid >> 6;
    int half = w >> 2, wq = w & 3;
    int q31 = lane & 31, h = lane >> 5;
    int sh = tid >> 8, sti = tid & 255;      // staging role: half, index-within-half
    int kvb = sh * 1024;

    // Q fragments (B-operand of mfma(K,Q))
    bf16x8 qf[4];
    {
        const u16* qp = Q + (size_t)(b * T + q0 + wq * 32 + q31) * D + hh * 64 + h * 8;
        #pragma unroll
        for (int ds = 0; ds < 4; ++ds)
            qf[ds] = *reinterpret_cast<const bf16x8*>(qp + ds * 16);
    }

    // per-thread staging pointers (row/slot constant; base advances 64 kv per tile)
    const u16* kp[2]; const u16* vp[2]; u16* ldk[2][2]; u16* ldv[2][2];
    #pragma unroll
    for (int c = 0; c < 2; ++c) {
        int ci = c * 256 + sti;
        int row = ci >> 3;
        int sl = (ci & 7) ^ swz8(row);
        kp[c] = K + (size_t)(b * T + kvb + row) * D + hh * 64 + sl * 8;
        vp[c] = Vt + (size_t)(bh * 64 + row) * T + kvb + sl * 8;
        ldk[0][c] = Ks[sh][0] + (size_t)ci * 8;  ldk[1][c] = Ks[sh][1] + (size_t)ci * 8;
        ldv[0][c] = Vs[sh][0] + (size_t)ci * 8;  ldv[1][c] = Vs[sh][1] + (size_t)ci * 8;
    }

    f32x16 o0, o1;
    #pragma unroll
    for (int e = 0; e < 16; ++e) { o0[e] = 0.0f; o1[e] = 0.0f; }
    float m_run = -1e30f, l_run = 0.0f;   // stats for q = q31 (log2 domain)

    // prologue: stage tile 0 of this thread's half into buffer 0
    #pragma unroll
    for (int c = 0; c < 2; ++c) {
        gload16(kp[c], ldk[0][c]);
        gload16(vp[c], ldv[0][c]);
        kp[c] += (size_t)64 * D;
        vp[c] += 64;
    }
    __syncthreads();

    for (int kt = 0; kt < 16; ++kt) {
        int cur = kt & 1;
        if (kt < 15) {   // issue next tile's loads under this tile's compute
            #pragma unroll
            for (int c = 0; c < 2; ++c) {
                gload16(kp[c], ldk[cur ^ 1][c]);
                gload16(vp[c], ldv[cur ^ 1][c]);
                kp[c] += (size_t)64 * D;
                vp[c] += 64;
            }
        }
        const char* Ksc = (const char*)Ks[half][cur];
        const char* Vsc = (const char*)Vs[half][cur];

        // S^T = mfma32(K, Q): lane holds S[q=q31][k = k2*32 + (reg&3)+8*(reg>>2)+4h]
        f32x16 s[2];
        #pragma unroll
        for (int k2 = 0; k2 < 2; ++k2)
            #pragma unroll
            for (int e = 0; e < 16; ++e) s[k2][e] = 0.0f;
        __builtin_amdgcn_s_setprio(1);
        #pragma unroll
        for (int k2 = 0; k2 < 2; ++k2) {
            int rk = k2 * 32 + q31;
            int xm = swz8(rk);
            #pragma unroll
            for (int ds = 0; ds < 4; ++ds) {
                int sp = (2 * ds + h) ^ xm;
                bf16x8 kf = *reinterpret_cast<const bf16x8*>(Ksc + rk * 128 + sp * 16);
                s[k2] = __builtin_amdgcn_mfma_f32_32x32x16_bf16(kf, qf[ds], s[k2], 0, 0, 0);
            }
        }
        __builtin_amdgcn_s_setprio(0);

        // lane-local softmax: 32 values + partner half via 1 shfl
        float mt = fmaxf(vmax16(s[0]), vmax16(s[1]));
        mt = fmaxf(mt, __shfl_xor(mt, 32, 64));
        bool skip = __all((int)(mt <= m_run + 11.0f));   // defer-max (T13)
        if (!skip) {
            float mn = fmaxf(m_run, mt);
            float corr = __builtin_exp2f(m_run - mn);
            m_run = mn;
            l_run *= corr;
            #pragma unroll
            for (int reg = 0; reg < 16; ++reg) {
                int src = ((reg & 3) + 8 * (reg >> 2)) + ((lane & 32) >> 3);
                float cr = __shfl(corr, src, 64);
                o0[reg] *= cr;
                o1[reg] *= cr;
            }
        }
        float ps0 = 0.0f, ps1 = 0.0f, ps2 = 0.0f, ps3 = 0.0f;
        #pragma unroll
        for (int k2 = 0; k2 < 2; ++k2)
            #pragma unroll
            for (int e = 0; e < 16; ++e) {
                float p = __builtin_exp2f(s[k2][e] - m_run);
                s[k2][e] = p;
                if ((e & 3) == 0) ps0 += p; else if ((e & 3) == 1) ps1 += p;
                else if ((e & 3) == 2) ps2 += p; else ps3 += p;
            }
        float psum = (ps0 + ps1) + (ps2 + ps3);
        psum += __shfl_xor(psum, 32, 64);
        l_run += psum;

        // pack P (cvt_pk + permlane32_swap) and accumulate O += P V
        __builtin_amdgcn_s_setprio(1);
        #pragma unroll
        for (int k2 = 0; k2 < 2; ++k2) {
            u32 w0 = cvtpk(s[k2][0], s[k2][1]),   w1 = cvtpk(s[k2][2], s[k2][3]);
            u32 w2 = cvtpk(s[k2][4], s[k2][5]),   w3 = cvtpk(s[k2][6], s[k2][7]);
            u32 w4 = cvtpk(s[k2][8], s[k2][9]),   w5 = cvtpk(s[k2][10], s[k2][11]);
            u32 w6 = cvtpk(s[k2][12], s[k2][13]), w7 = cvtpk(s[k2][14], s[k2][15]);
            plswap(w0, w2); plswap(w1, w3);   // t-slice 2*k2 frag
            plswap(w4, w6); plswap(w5, w7);   // t-slice 2*k2+1 frag
            union { bf16x8 v; u32 u[4]; } plo, phi;
            plo.u[0] = w0; plo.u[1] = w1; plo.u[2] = w2; plo.u[3] = w3;
            phi.u[0] = w4; phi.u[1] = w5; phi.u[2] = w6; phi.u[3] = w7;
            int rv0 = q31, rv1 = 32 + q31;
            int x0 = swz8(rv0), x1 = swz8(rv1);
            int klo = 2 * k2, khi = 2 * k2 + 1;
            bf16x8 vf;
            vf = *reinterpret_cast<const bf16x8*>(Vsc + rv0 * 128 + (((2 * klo + h) ^ x0) << 4));
            o0 = __builtin_amdgcn_mfma_f32_32x32x16_bf16(plo.v, vf, o0, 0, 0, 0);
            vf = *reinterpret_cast<const bf16x8*>(Vsc + rv1 * 128 + (((2 * klo + h) ^ x1) << 4));
            o1 = __builtin_amdgcn_mfma_f32_32x32x16_bf16(plo.v, vf, o1, 0, 0, 0);
            vf = *reinterpret_cast<const bf16x8*>(Vsc + rv0 * 128 + (((2 * khi + h) ^ x0) << 4));
            o0 = __builtin_amdgcn_mfma_f32_32x32x16_bf16(phi.v, vf, o0, 0, 0, 0);
            vf = *reinterpret_cast<const bf16x8*>(Vsc + rv1 * 128 + (((2 * khi + h) ^ x1) << 4));
            o1 = __builtin_amdgcn_mfma_f32_32x32x16_bf16(phi.v, vf, o1, 0, 0, 0);
        }
        __builtin_amdgcn_s_setprio(0);
        __syncthreads();   // drains vmcnt(0): next tile staged & visible; cur buffer free
    }

    // ---- split-KV merge through freed LDS (exact online-softmax combine) ----
    float* ML = (float*)Ks;   // [wq][2][32] : m, l per q31
    float* OB = (float*)Vs;   // [wq][row 0..31][d 0..63] partial O of half 1 (32 KB)
    if (half == 1) {
        if (h == 0) {
            ML[(wq * 2 + 0) * 32 + q31] = m_run;
            ML[(wq * 2 + 1) * 32 + q31] = l_run;
        }
        #pragma unroll
        for (int reg = 0; reg < 16; ++reg) {
            int row = (reg & 3) + 8 * (reg >> 2) + 4 * h;
            OB[((size_t)wq * 32 + row) * 64 + q31] = o0[reg];
            OB[((size_t)wq * 32 + row) * 64 + 32 + q31] = o1[reg];
        }
    }
    __syncthreads();
    if (half == 0) {
        float mB = ML[(wq * 2 + 0) * 32 + q31];
        float lB = ML[(wq * 2 + 1) * 32 + q31];
        float mn = fmaxf(m_run, mB);
        float ca = __builtin_exp2f(m_run - mn);
        float cb = __builtin_exp2f(mB - mn);
        float lf = ca * l_run + cb * lB;
        float fa = ca / lf, fb = cb / lf;
        #pragma unroll
        for (int reg = 0; reg < 16; ++reg) {
            int src = ((reg & 3) + 8 * (reg >> 2)) + ((lane & 32) >> 3);
            float far = __shfl(fa, src, 64);
            float fbr = __shfl(fb, src, 64);
            int row = (reg & 3) + 8 * (reg >> 2) + 4 * h;
            float b0 = OB[((size_t)wq * 32 + row) * 64 + q31];
            float b1 = OB[((size_t)wq * 32 + row) * 64 + 32 + q31];
            int qr = q0 + wq * 32 + row;
            size_t off = (size_t)(b * T + qr) * D + hh * 64 + q31;
            AO[off] = f2bf(o0[reg] * far + b0 * fbr);
            AO[off + 32] = f2bf(o1[reg] * far + b1 * fbr);
        }
    }
}

// ---------------- output projection + bias + residual (bf16 residual in, bf16 y out) ----------------
__global__ __launch_bounds__(256, 2)
void k_ogemm(const u16* __restrict__ A, const u16* __restrict__ Wt,
             const float* __restrict__ bo, const u16* __restrict__ xpeb,
             u16* __restrict__ y)
{
    int m0 = blockIdx.x * 128, n0 = blockIdx.y * 128;
    f32x16 acc[2][2];
    gemm128(A, Wt, m0, n0, acc);
    int lane = threadIdx.x & 63, wave = threadIdx.x >> 6;
    int wr = wave >> 1, wc = wave & 1;
    int l31 = lane & 31, hb = lane >> 5;
    #pragma unroll
    for (int ni = 0; ni < 2; ++ni) {
        int c = n0 + wc * 64 + ni * 32 + l31;
        float bc = bo[c];
        #pragma unroll
        for (int mi = 0; mi < 2; ++mi) {
            #pragma unroll
            for (int reg = 0; reg < 16; ++reg) {
                int r = m0 + wr * 64 + mi * 32 + (reg & 3) + 8 * (reg >> 2) + 4 * hb;
                float res = bf2f(xpeb[(size_t)r * D + c]);
                y[(size_t)r * D + c] = f2bf(acc[mi][ni][reg] + bc + res);
            }
        }
    }
}

// ---------------- LayerNorm (bf16 input, fp32 output) ----------------
__global__ __launch_bounds__(256) void k_ln(const u16* __restrict__ y, const float* __restrict__ g,
                                            const float* __restrict__ bb, float* __restrict__ out)
{
    int row = blockIdx.x;
    int tid = threadIdx.x;
    const u16* yr = y + (size_t)row * D;
    ushort4 v4 = *reinterpret_cast<const ushort4*>(yr + tid * 4);
    float v0 = bf2f(v4.x), v1 = bf2f(v4.y), v2 = bf2f(v4.z), v3 = bf2f(v4.w);
    float s = (v0 + v1) + (v2 + v3);
    float s2 = (v0 * v0 + v1 * v1) + (v2 * v2 + v3 * v3);
    #pragma unroll
    for (int off = 1; off < 64; off <<= 1) {
        s += __shfl_xor(s, off, 64);
        s2 += __shfl_xor(s2, off, 64);
    }
    __shared__ float red[8];
    int wave = tid >> 6, lane = tid & 63;
    if (lane == 0) { red[wave] = s; red[4 + wave] = s2; }
    __syncthreads();
    s = red[0] + red[1] + red[2] + red[3];
    s2 = red[4] + red[5] + red[6] + red[7];
    float mu = s * (1.0f / 1024.0f);
    float var = s2 * (1.0f / 1024.0f) - mu * mu;
    float rstd = rsqrtf(var + 1e-5f);
    float4 gv = *reinterpret_cast<const float4*>(g + tid * 4);
    float4 bv = *reinterpret_cast<const float4*>(bb + tid * 4);
    float4 o;
    o.x = (v0 - mu) * rstd * gv.x + bv.x;
    o.y = (v1 - mu) * rstd * gv.y + bv.y;
    o.z = (v2 - mu) * rstd * gv.z + bv.z;
    o.w = (v3 - mu) * rstd * gv.w + bv.w;
    *reinterpret_cast<float4*>(out + (size_t)row * D + tid * 4) = o;
}

extern "C" void kernel_launch(void* const* d_in, const int* in_sizes, int n_in,
                              void* d_out, int out_size, void* d_ws, size_t ws_size,
                              hipStream_t stream)
{
    const float* x    = (const float*)d_in[0];
    const float* qtl  = (const float*)d_in[1];
    const float* qimp = (const float*)d_in[2];
    const float* Wq = (const float*)d_in[3];
    const float* bq = (const float*)d_in[4];
    const float* Wk = (const float*)d_in[5];
    const float* bk = (const float*)d_in[6];
    const float* Wv = (const float*)d_in[7];
    const float* bv = (const float*)d_in[8];
    const float* Wo = (const float*)d_in[9];
    const float* bo = (const float*)d_in[10];
    const float* qpq_w1 = (const float*)d_in[11];
    const float* qpq_b1 = (const float*)d_in[12];
    const float* qpq_w2 = (const float*)d_in[13];
    const float* qpq_b2 = (const float*)d_in[14];
    const float* qpk_w1 = (const float*)d_in[15];
    const float* qpk_b1 = (const float*)d_in[16];
    const float* qpk_w2 = (const float*)d_in[17];
    const float* qpk_b2 = (const float*)d_in[18];
    const float* qpv_w1 = (const float*)d_in[19];
    const float* qpv_b1 = (const float*)d_in[20];
    const float* qpv_w2 = (const float*)d_in[21];
    const float* qpv_b2 = (const float*)d_in[22];
    const float* ln_g = (const float*)d_in[23];
    const float* ln_b = (const float*)d_in[24];
    (void)in_sizes; (void)n_in; (void)out_size; (void)ws_size;

    char* w = (char*)d_ws;
    u16* xpeb    = (u16*)(w);                           // 8 MB bf16 x+PE (also residual)
    u16* Wt      = (u16*)(w + (8u << 20));              // 8 MB: Wq,Wk,Wv,Wo transposed bf16
    u16* Qb      = (u16*)(w + (16u << 20));             // 8 MB bf16 [NR][D]
    u16* Kb      = (u16*)(w + (24u << 20));             // 8 MB bf16 [NR][D]
    u16* Vtb     = (u16*)(w + (32u << 20));             // 8 MB bf16 [B*NH*64][T]
    u16* AOb     = (u16*)(w + (40u << 20));             // 8 MB bf16 [NR][D]
    u16* yb      = (u16*)(w + (16u << 20));             // 8 MB bf16, aliases Qb (dead after attn)
    float* emb   = (float*)(w + (48u << 20));           // [3][B][D]
    float* scl   = (float*)(w + (48u << 20) + 32768);   // [B]

    k_prep<<<5144, 256, 0, stream>>>(x, xpeb, Wq, Wk, Wv, Wo, Wt,
        qtl, qimp,
        qpq_w1, qpq_b1, qpq_w2, qpq_b2,
        qpk_w1, qpk_b1, qpk_w2, qpk_b2,
        qpv_w1, qpv_b1, qpv_w2, qpv_b2,
        emb, scl);
    k_qkv<<<dim3(32, 8, 3), 256, 0, stream>>>(xpeb, Wt, bq, bk, bv, emb, scl, Qb, Kb, Vtb);
    k_attn<<<dim3(32, 16), 512, 0, stream>>>(Qb, Kb, Vtb, AOb);
    k_ogemm<<<dim3(32, 8), 256, 0, stream>>>(AOb, Wt + (size_t)3 * D * D, bo, xpeb, yb);
    k_ln<<<4096, 256, 0, stream>>>(yb, ln_g, ln_b, (float*)d_out);
}

// Round 15
// 148.747 us; speedup vs baseline: 1.1990x; 1.1990x over previous
//
#include <hip/hip_runtime.h>

#define D 1024
#define T 2048
#define BATCH 2
#define NR 4096
#define NH 16
#define HID 512

typedef unsigned short u16;
typedef unsigned int u32;
typedef unsigned long long u64;
typedef float f32x4 __attribute__((ext_vector_type(4)));
typedef float f32x16 __attribute__((ext_vector_type(16)));
typedef __bf16 bf16x8 __attribute__((ext_vector_type(8)));

// native RNE f32->bf16 (hardware v_cvt)
__device__ __forceinline__ u16 f2bf(float f) {
    union { __bf16 h; u16 u; } c; c.h = (__bf16)f; return c.u;
}

// pack two f32 -> 2xbf16 in one u32 (low = a, high = b). No builtin on gfx950 (m240).
__device__ __forceinline__ u32 cvtpk(float a, float b) {
    u32 r;
    asm("v_cvt_pk_bf16_f32 %0, %1, %2" : "=v"(r) : "v"(a), "v"(b));
    return r;
}

// v_permlane32_swap_b32: x[32..63] <-> y[0..31].
__device__ __forceinline__ void plswap(u32& x, u32& y) {
    asm volatile("v_permlane32_swap_b32 %0, %1" : "+v"(x), "+v"(y));
}

__device__ __forceinline__ float fmax3(float a, float b, float c) {
    float r; asm("v_max3_f32 %0, %1, %2, %3" : "=v"(r) : "v"(a), "v"(b), "v"(c)); return r;
}

// max over an f32x16 with ILP tree (8 ops)
__device__ __forceinline__ float vmax16(const f32x16& v) {
    float c0 = fmax3(v[0], v[1], v[2]);
    float c1 = fmax3(v[3], v[4], v[5]);
    float c2 = fmax3(v[6], v[7], v[8]);
    float c3 = fmax3(v[9], v[10], v[11]);
    c0 = fmax3(c0, v[12], v[13]);
    c1 = fmax3(c1, v[14], v[15]);
    c0 = fmax3(c0, c1, c2);
    return fmaxf(c0, c3);
}

// async global->LDS, 16B per lane. LDS dest lane-linear; read-side XOR swizzle realized
// by pre-swizzling the GLOBAL source column (both-sides-or-neither).
__device__ __forceinline__ void gload16(const u16* g, u16* l) {
    __builtin_amdgcn_global_load_lds(
        (const __attribute__((address_space(1))) unsigned int*)g,
        (__attribute__((address_space(3))) unsigned int*)l,
        16, 0, 0);
}

// conflict-free slot swizzle for 8-slot (128B) rows read at 32-row stride
__device__ __forceinline__ int swz8(int row) {
    return (row & 7) ^ ((row >> 3) & 3);
}

// ---------------- quantile MLP stage 1: partial sums + importance scale ----------------
__global__ __launch_bounds__(256) void k_mlp1(const float* __restrict__ qtl,
        const float* __restrict__ w1q, const float* __restrict__ b1q, const float* __restrict__ w2q,
        const float* __restrict__ w1k, const float* __restrict__ b1k, const float* __restrict__ w2k,
        const float* __restrict__ w1v, const float* __restrict__ b1v, const float* __restrict__ w2v,
        const float* __restrict__ qimp, float* __restrict__ part, float* __restrict__ scl)
{
    int dc = blockIdx.x;       // 0..3  (256 d each)
    int jc = blockIdx.y;       // 0..3  (128 j each)
    int wb = blockIdx.z;       // 0..5 : which*2 + b
    int which = wb >> 1, b = wb & 1;
    const float *w1, *b1, *w2;
    if (which == 0)      { w1 = w1q; b1 = b1q; w2 = w2q; }
    else if (which == 1) { w1 = w1k; b1 = b1k; w2 = w2k; }
    else                 { w1 = w1v; b1 = b1v; w2 = w2v; }
    int tid = threadIdx.x;
    __shared__ float h[128];
    if (tid < 128) {
        int j = jc * 128 + tid;
        h[tid] = fmaxf(qtl[b] * w1[j] + b1[j], 0.0f);
    }
    __syncthreads();
    int d = dc * 256 + tid;
    float acc = 0.0f;
    for (int j = 0; j < 128; ++j) acc += h[j] * w2[(size_t)(jc * 128 + j) * D + d];
    part[((size_t)wb * 4 + jc) * D + d] = acc;
    if (dc == 0 && jc == 0 && wb == 0 && tid < BATCH) {
        float mx = qimp[0];
        for (int i = 1; i < 100; ++i) mx = fmaxf(mx, qimp[i]);
        float q = qtl[tid];
        int idx = (int)(q * 100.0f);
        idx = idx < 0 ? 0 : (idx > 99 ? 99 : idx);
        float imp = qimp[idx];
        if (mx > 0.0f) imp /= mx;
        scl[tid] = 1.0f + imp;
    }
}

// ---------------- quantile MLP stage 2: reduce partials + bias ----------------
__global__ __launch_bounds__(256) void k_mlp2(const float* __restrict__ part,
        const float* __restrict__ b2q, const float* __restrict__ b2k, const float* __restrict__ b2v,
        float* __restrict__ embeds)
{
    int dc = blockIdx.x;   // 0..3
    int wb = blockIdx.y;   // 0..5
    int which = wb >> 1;
    const float* b2 = which == 0 ? b2q : which == 1 ? b2k : b2v;
    int d = dc * 256 + threadIdx.x;
    float acc = b2[d];
    #pragma unroll
    for (int jc = 0; jc < 4; ++jc) acc += part[((size_t)wb * 4 + jc) * D + d];
    embeds[(size_t)wb * D + d] = acc;   // [which][b][d]
}

// ---- fused: x+PE (blocks 0..4095) | weight transpose+bf16 (blocks 4096..5119) ----
__global__ __launch_bounds__(256) void k_prep(const float* __restrict__ x,
                                              float* __restrict__ xpe, u16* __restrict__ xpeb,
                                              const float* __restrict__ Wq, const float* __restrict__ Wk,
                                              const float* __restrict__ Wv, const float* __restrict__ Wo,
                                              u16* __restrict__ Wt)
{
    if (blockIdx.x < 4096) {
        int idx = (blockIdx.x * 256 + threadIdx.x) * 4;
        int d = idx & (D - 1);
        int t = (idx >> 10) & (T - 1);
        const float KL = -0.0089944731946f;  // -ln(10000)/1024
        float ft = (float)t;
        float dv0 = __expf((float)d * KL);
        float dv1 = __expf((float)(d + 2) * KL);
        float a0 = ft * dv0, a1 = ft * dv1;
        float4 xv = *reinterpret_cast<const float4*>(x + idx);
        float4 r;
        r.x = xv.x + __sinf(a0);
        r.y = xv.y + __cosf(a0);
        r.z = xv.z + __sinf(a1);
        r.w = xv.w + __cosf(a1);
        *reinterpret_cast<float4*>(xpe + idx) = r;
        ushort4 o;
        o.x = f2bf(r.x); o.y = f2bf(r.y); o.z = f2bf(r.z); o.w = f2bf(r.w);
        *reinterpret_cast<ushort4*>(xpeb + idx) = o;
        return;
    }
    __shared__ float tile[64][65];
    int bi = blockIdx.x - 4096;
    int z = bi >> 8;
    const float* W = z == 0 ? Wq : z == 1 ? Wk : z == 2 ? Wv : Wo;
    u16* out = Wt + (size_t)z * D * D;
    int n0 = (bi & 15) * 64, k0 = ((bi >> 4) & 15) * 64;
    int r = threadIdx.x >> 4;
    int c4 = (threadIdx.x & 15) * 4;
    #pragma unroll
    for (int rr = 0; rr < 64; rr += 16) {
        float4 v = *reinterpret_cast<const float4*>(W + (size_t)(k0 + r + rr) * D + n0 + c4);
        tile[r + rr][c4 + 0] = v.x; tile[r + rr][c4 + 1] = v.y;
        tile[r + rr][c4 + 2] = v.z; tile[r + rr][c4 + 3] = v.w;
    }
    __syncthreads();
    #pragma unroll
    for (int rr = 0; rr < 64; rr += 16) {
        ushort4 o;
        o.x = f2bf(tile[c4 + 0][r + rr]);
        o.y = f2bf(tile[c4 + 1][r + rr]);
        o.z = f2bf(tile[c4 + 2][r + rr]);
        o.w = f2bf(tile[c4 + 3][r + rr]);
        *reinterpret_cast<ushort4*>(out + (size_t)(n0 + r + rr) * D + k0 + c4) = o;
    }
}

// ---------------- shared 128x128 GEMM core: 32x32x16 MFMA, single 32KB buffer ----------------
// A[m][k] row-major bf16, B = Wt[n][k] row-major bf16 (B^T layout). 4 waves, each owns a
// 64x64 output (2x2 of 32x32). C/D map: row=(reg&3)+8*(reg>>2)+4*(lane>>5), col=lane&31.
__device__ __forceinline__ void gemm128(const u16* __restrict__ Ag, const u16* __restrict__ Bg,
                                        int m0, int n0, f32x16 acc[2][2])
{
    __shared__ u16 As[128 * 64];
    __shared__ u16 Bs[128 * 64];
    const int tid = threadIdx.x;
    const int lane = tid & 63, wave = tid >> 6;
    const int wr = wave >> 1, wc = wave & 1;
    const int l31 = lane & 31, hb = lane >> 5;
    #pragma unroll
    for (int mi = 0; mi < 2; ++mi)
        #pragma unroll
        for (int ni = 0; ni < 2; ++ni)
            #pragma unroll
            for (int e = 0; e < 16; ++e) acc[mi][ni][e] = 0.0f;

    for (int kt = 0; kt < 16; ++kt) {
        __syncthreads();   // prev tile fully consumed by all waves
        #pragma unroll
        for (int c = 0; c < 4; ++c) {
            int ci = c * 256 + tid;
            int row = ci >> 3;
            int sl = (ci & 7) ^ swz8(row);   // pre-swizzled global column slot
            gload16(Ag + (size_t)(m0 + row) * D + kt * 64 + sl * 8, As + (size_t)ci * 8);
            gload16(Bg + (size_t)(n0 + row) * D + kt * 64 + sl * 8, Bs + (size_t)ci * 8);
        }
        __syncthreads();   // drains vmcnt(0): staged data visible to all
        #pragma unroll
        for (int ks = 0; ks < 4; ++ks) {
            bf16x8 af[2], bfr[2];
            #pragma unroll
            for (int mi = 0; mi < 2; ++mi) {
                int ra = wr * 64 + mi * 32 + l31;
                int sa = (2 * ks + hb) ^ swz8(ra);
                af[mi] = *reinterpret_cast<const bf16x8*>((const char*)As + ra * 128 + sa * 16);
                int rb = wc * 64 + mi * 32 + l31;
                int sb = (2 * ks + hb) ^ swz8(rb);
                bfr[mi] = *reinterpret_cast<const bf16x8*>((const char*)Bs + rb * 128 + sb * 16);
            }
            #pragma unroll
            for (int mi = 0; mi < 2; ++mi)
                #pragma unroll
                for (int ni = 0; ni < 2; ++ni)
                    acc[mi][ni] = __builtin_amdgcn_mfma_f32_32x32x16_bf16(af[mi], bfr[ni], acc[mi][ni], 0, 0, 0);
        }
    }
}

// ---------------- Q/K/V projections (Q pre-scaled by scl[b]*log2(e)/sqrt(dk)) ----------------
__global__ __launch_bounds__(256, 2)
void k_qkv(const u16* __restrict__ A, const u16* __restrict__ Wt,
           const float* __restrict__ bq, const float* __restrict__ bk, const float* __restrict__ bv,
           const float* __restrict__ embeds, const float* __restrict__ scl,
           u16* __restrict__ Qo, u16* __restrict__ Ko, u16* __restrict__ Vt)
{
    int which = blockIdx.z;
    const u16* Bg = Wt + (size_t)which * D * D;
    const float* bias = which == 0 ? bq : which == 1 ? bk : bv;
    const float* emb = embeds + which * (BATCH * D);
    int m0 = blockIdx.x * 128, n0 = blockIdx.y * 128;
    f32x16 acc[2][2];
    gemm128(A, Bg, m0, n0, acc);
    int lane = threadIdx.x & 63, wave = threadIdx.x >> 6;
    int wr = wave >> 1, wc = wave & 1;
    int l31 = lane & 31, hb = lane >> 5;
    if (which < 2) {
        u16* Out = which == 0 ? Qo : Ko;
        float sc0 = 1.0f, sc1 = 1.0f;
        if (which == 0) {
            sc0 = scl[0] * 0.125f * 1.44269504f;   // fold 1/sqrt(dk) * temp-scale * log2(e)
            sc1 = scl[1] * 0.125f * 1.44269504f;
        }
        #pragma unroll
        for (int ni = 0; ni < 2; ++ni) {
            int c = n0 + wc * 64 + ni * 32 + l31;
            float add0 = bias[c] + emb[c];
            float add1 = bias[c] + emb[D + c];
            #pragma unroll
            for (int mi = 0; mi < 2; ++mi) {
                #pragma unroll
                for (int reg = 0; reg < 16; ++reg) {
                    int r = m0 + wr * 64 + mi * 32 + (reg & 3) + 8 * (reg >> 2) + 4 * hb;
                    float v = (r >> 11) ? (acc[mi][ni][reg] + add1) * sc1
                                        : (acc[mi][ni][reg] + add0) * sc0;
                    Out[(size_t)r * D + c] = f2bf(v);
                }
            }
        }
    } else {
        // V stored transposed per-head: Vt[((b*NH + h)*64 + cc)][t]; reg&3 axis = 4 consecutive t
        #pragma unroll
        for (int ni = 0; ni < 2; ++ni) {
            int c = n0 + wc * 64 + ni * 32 + l31;
            int hh = c >> 6, cc = c & 63;
            float add0 = bias[c] + emb[c];
            float add1 = bias[c] + emb[D + c];
            #pragma unroll
            for (int mi = 0; mi < 2; ++mi) {
                #pragma unroll
                for (int g2 = 0; g2 < 4; ++g2) {
                    int r = m0 + wr * 64 + mi * 32 + 8 * g2 + 4 * hb;
                    int bb = r >> 11;
                    int t = r & (T - 1);
                    float add = bb ? add1 : add0;
                    ushort4 o;
                    o.x = f2bf(acc[mi][ni][4 * g2 + 0] + add);
                    o.y = f2bf(acc[mi][ni][4 * g2 + 1] + add);
                    o.z = f2bf(acc[mi][ni][4 * g2 + 2] + add);
                    o.w = f2bf(acc[mi][ni][4 * g2 + 3] + add);
                    *reinterpret_cast<ushort4*>(Vt + ((size_t)((bb * NH + hh) * 64 + cc)) * T + t) = o;
                }
            }
        }
    }
}

// ---------------- flash attention: split-KV, 8 waves (2 halves x 4 q-waves), KVBLK=64 ----------------
// R6 structure (best measured): LDS-staged K/V, stage-ahead dbuf, swz8 conflict-free swizzle,
// 32x32x16 MFMA, swapped QK^T, in-register P via cvt_pk + permlane32_swap, split-KV LDS merge.
__global__ __launch_bounds__(512, 4)
void k_attn(const u16* __restrict__ Q, const u16* __restrict__ K, const u16* __restrict__ Vt,
            u16* __restrict__ AO)
{
    __shared__ u16 Ks[2][2][64 * 64];   // [half][dbuf][t=64][d=64], 8x16B slots/row
    __shared__ u16 Vs[2][2][64 * 64];   // [half][dbuf][d=64][t=64], 8x16B slots/row
    int bh = blockIdx.x;
    int b = bh >> 4, hh = bh & 15;
    int q0 = blockIdx.y * 128;
    int tid = threadIdx.x;
    int lane = tid & 63, w = tid >> 6;
    int half = w >> 2, wq = w & 3;
    int q31 = lane & 31, h = lane >> 5;
    int sh = tid >> 8, sti = tid & 255;      // staging role: half, index-within-half
    int kvb = sh * 1024;

    // Q fragments (B-operand of mfma(K,Q))
    bf16x8 qf[4];
    {
        const u16* qp = Q + (size_t)(b * T + q0 + wq * 32 + q31) * D + hh * 64 + h * 8;
        #pragma unroll
        for (int ds = 0; ds < 4; ++ds)
            qf[ds] = *reinterpret_cast<const bf16x8*>(qp + ds * 16);
    }

    f32x16 o0, o1;
    #pragma unroll
    for (int e = 0; e < 16; ++e) { o0[e] = 0.0f; o1[e] = 0.0f; }
    float m_run = -1e30f, l_run = 0.0f;   // stats for q = q31 (log2 domain)

    // prologue: stage tile 0 of this thread's half
    #pragma unroll
    for (int c = 0; c < 2; ++c) {
        int ci = c * 256 + sti;
        int row = ci >> 3;
        int sl = (ci & 7) ^ swz8(row);
        gload16(K + (size_t)(b * T + kvb + row) * D + hh * 64 + sl * 8, Ks[sh][0] + (size_t)ci * 8);
        gload16(Vt + (size_t)(bh * 64 + row) * T + kvb + sl * 8, Vs[sh][0] + (size_t)ci * 8);
    }
    __syncthreads();

    for (int kt = 0; kt < 16; ++kt) {
        int cur = kt & 1;
        if (kt < 15) {   // issue next tile's loads under this tile's compute
            int t0 = kvb + (kt + 1) * 64;
            #pragma unroll
            for (int c = 0; c < 2; ++c) {
                int ci = c * 256 + sti;
                int row = ci >> 3;
                int sl = (ci & 7) ^ swz8(row);
                gload16(K + (size_t)(b * T + t0 + row) * D + hh * 64 + sl * 8, Ks[sh][cur ^ 1] + (size_t)ci * 8);
                gload16(Vt + (size_t)(bh * 64 + row) * T + t0 + sl * 8, Vs[sh][cur ^ 1] + (size_t)ci * 8);
            }
        }
        const char* Ksc = (const char*)Ks[half][cur];
        const char* Vsc = (const char*)Vs[half][cur];

        // S^T = mfma32(K, Q): lane holds S[q=q31][k = k2*32 + (reg&3)+8*(reg>>2)+4h]
        f32x16 s[2];
        #pragma unroll
        for (int k2 = 0; k2 < 2; ++k2)
            #pragma unroll
            for (int e = 0; e < 16; ++e) s[k2][e] = 0.0f;
        __builtin_amdgcn_s_setprio(1);
        #pragma unroll
        for (int k2 = 0; k2 < 2; ++k2) {
            int rk = k2 * 32 + q31;
            int xm = swz8(rk);
            #pragma unroll
            for (int ds = 0; ds < 4; ++ds) {
                int sp = (2 * ds + h) ^ xm;
                bf16x8 kf = *reinterpret_cast<const bf16x8*>(Ksc + rk * 128 + sp * 16);
                s[k2] = __builtin_amdgcn_mfma_f32_32x32x16_bf16(kf, qf[ds], s[k2], 0, 0, 0);
            }
        }
        __builtin_amdgcn_s_setprio(0);

        // lane-local softmax: 32 values + partner half via 1 shfl
        float mt = fmaxf(vmax16(s[0]), vmax16(s[1]));
        mt = fmaxf(mt, __shfl_xor(mt, 32, 64));
        bool skip = __all((int)(mt <= m_run + 11.0f));   // defer-max (T13)
        if (!skip) {
            float mn = fmaxf(m_run, mt);
            float corr = __builtin_exp2f(m_run - mn);
            m_run = mn;
            l_run *= corr;
            #pragma unroll
            for (int reg = 0; reg < 16; ++reg) {
                int src = ((reg & 3) + 8 * (reg >> 2)) + ((lane & 32) >> 3);
                float cr = __shfl(corr, src, 64);
                o0[reg] *= cr;
                o1[reg] *= cr;
            }
        }
        float ps0 = 0.0f, ps1 = 0.0f, ps2 = 0.0f, ps3 = 0.0f;
        #pragma unroll
        for (int k2 = 0; k2 < 2; ++k2)
            #pragma unroll
            for (int e = 0; e < 16; ++e) {
                float p = __builtin_exp2f(s[k2][e] - m_run);
                s[k2][e] = p;
                if ((e & 3) == 0) ps0 += p; else if ((e & 3) == 1) ps1 += p;
                else if ((e & 3) == 2) ps2 += p; else ps3 += p;
            }
        float psum = (ps0 + ps1) + (ps2 + ps3);
        psum += __shfl_xor(psum, 32, 64);
        l_run += psum;

        // pack P (cvt_pk + permlane32_swap) and accumulate O += P V
        __builtin_amdgcn_s_setprio(1);
        #pragma unroll
        for (int k2 = 0; k2 < 2; ++k2) {
            u32 w0 = cvtpk(s[k2][0], s[k2][1]),   w1 = cvtpk(s[k2][2], s[k2][3]);
            u32 w2 = cvtpk(s[k2][4], s[k2][5]),   w3 = cvtpk(s[k2][6], s[k2][7]);
            u32 w4 = cvtpk(s[k2][8], s[k2][9]),   w5 = cvtpk(s[k2][10], s[k2][11]);
            u32 w6 = cvtpk(s[k2][12], s[k2][13]), w7 = cvtpk(s[k2][14], s[k2][15]);
            plswap(w0, w2); plswap(w1, w3);   // t-slice 2*k2 frag
            plswap(w4, w6); plswap(w5, w7);   // t-slice 2*k2+1 frag
            union { bf16x8 v; u32 u[4]; } plo, phi;
            plo.u[0] = w0; plo.u[1] = w1; plo.u[2] = w2; plo.u[3] = w3;
            phi.u[0] = w4; phi.u[1] = w5; phi.u[2] = w6; phi.u[3] = w7;
            int rv0 = q31, rv1 = 32 + q31;
            int x0 = swz8(rv0), x1 = swz8(rv1);
            int klo = 2 * k2, khi = 2 * k2 + 1;
            bf16x8 vf;
            vf = *reinterpret_cast<const bf16x8*>(Vsc + rv0 * 128 + (((2 * klo + h) ^ x0) << 4));
            o0 = __builtin_amdgcn_mfma_f32_32x32x16_bf16(plo.v, vf, o0, 0, 0, 0);
            vf = *reinterpret_cast<const bf16x8*>(Vsc + rv1 * 128 + (((2 * klo + h) ^ x1) << 4));
            o1 = __builtin_amdgcn_mfma_f32_32x32x16_bf16(plo.v, vf, o1, 0, 0, 0);
            vf = *reinterpret_cast<const bf16x8*>(Vsc + rv0 * 128 + (((2 * khi + h) ^ x0) << 4));
            o0 = __builtin_amdgcn_mfma_f32_32x32x16_bf16(phi.v, vf, o0, 0, 0, 0);
            vf = *reinterpret_cast<const bf16x8*>(Vsc + rv1 * 128 + (((2 * khi + h) ^ x1) << 4));
            o1 = __builtin_amdgcn_mfma_f32_32x32x16_bf16(phi.v, vf, o1, 0, 0, 0);
        }
        __builtin_amdgcn_s_setprio(0);
        __syncthreads();   // drains vmcnt(0): next tile staged & visible; cur buffer free
    }

    // ---- split-KV merge through freed LDS (exact online-softmax combine) ----
    float* ML = (float*)Ks;   // [wq][2][32] : m, l per q31
    float* OB = (float*)Vs;   // [wq][row 0..31][d 0..63] partial O of half 1 (32 KB)
    if (half == 1) {
        if (h == 0) {
            ML[(wq * 2 + 0) * 32 + q31] = m_run;
            ML[(wq * 2 + 1) * 32 + q31] = l_run;
        }
        #pragma unroll
        for (int reg = 0; reg < 16; ++reg) {
            int row = (reg & 3) + 8 * (reg >> 2) + 4 * h;
            OB[((size_t)wq * 32 + row) * 64 + q31] = o0[reg];
            OB[((size_t)wq * 32 + row) * 64 + 32 + q31] = o1[reg];
        }
    }
    __syncthreads();
    if (half == 0) {
        float mB = ML[(wq * 2 + 0) * 32 + q31];
        float lB = ML[(wq * 2 + 1) * 32 + q31];
        float mn = fmaxf(m_run, mB);
        float ca = __builtin_exp2f(m_run - mn);
        float cb = __builtin_exp2f(mB - mn);
        float lf = ca * l_run + cb * lB;
        float fa = ca / lf, fb = cb / lf;
        #pragma unroll
        for (int reg = 0; reg < 16; ++reg) {
            int src = ((reg & 3) + 8 * (reg >> 2)) + ((lane & 32) >> 3);
            float far = __shfl(fa, src, 64);
            float fbr = __shfl(fb, src, 64);
            int row = (reg & 3) + 8 * (reg >> 2) + 4 * h;
            float b0 = OB[((size_t)wq * 32 + row) * 64 + q31];
            float b1 = OB[((size_t)wq * 32 + row) * 64 + 32 + q31];
            int qr = q0 + wq * 32 + row;
            size_t off = (size_t)(b * T + qr) * D + hh * 64 + q31;
            AO[off] = f2bf(o0[reg] * far + b0 * fbr);
            AO[off + 32] = f2bf(o1[reg] * far + b1 * fbr);
        }
    }
}

// ---------------- output projection + bias + residual ----------------
__global__ __launch_bounds__(256, 2)
void k_ogemm(const u16* __restrict__ A, const u16* __restrict__ Wt,
             const float* __restrict__ bo, const float* __restrict__ xpe,
             float* __restrict__ y)
{
    int m0 = blockIdx.x * 128, n0 = blockIdx.y * 128;
    f32x16 acc[2][2];
    gemm128(A, Wt, m0, n0, acc);
    int lane = threadIdx.x & 63, wave = threadIdx.x >> 6;
    int wr = wave >> 1, wc = wave & 1;
    int l31 = lane & 31, hb = lane >> 5;
    #pragma unroll
    for (int ni = 0; ni < 2; ++ni) {
        int c = n0 + wc * 64 + ni * 32 + l31;
        float bc = bo[c];
        #pragma unroll
        for (int mi = 0; mi < 2; ++mi) {
            #pragma unroll
            for (int reg = 0; reg < 16; ++reg) {
                int r = m0 + wr * 64 + mi * 32 + (reg & 3) + 8 * (reg >> 2) + 4 * hb;
                y[(size_t)r * D + c] = acc[mi][ni][reg] + bc + xpe[(size_t)r * D + c];
            }
        }
    }
}

// ---------------- LayerNorm ----------------
__global__ __launch_bounds__(256) void k_ln(const float* __restrict__ y, const float* __restrict__ g,
                                            const float* __restrict__ bb, float* __restrict__ out)
{
    int row = blockIdx.x;
    int tid = threadIdx.x;
    const float* yr = y + (size_t)row * D;
    float4 v = *reinterpret_cast<const float4*>(yr + tid * 4);
    float s = v.x + v.y + v.z + v.w;
    float s2 = v.x * v.x + v.y * v.y + v.z * v.z + v.w * v.w;
    #pragma unroll
    for (int off = 1; off < 64; off <<= 1) {
        s += __shfl_xor(s, off, 64);
        s2 += __shfl_xor(s2, off, 64);
    }
    __shared__ float red[8];
    int wave = tid >> 6, lane = tid & 63;
    if (lane == 0) { red[wave] = s; red[4 + wave] = s2; }
    __syncthreads();
    s = red[0] + red[1] + red[2] + red[3];
    s2 = red[4] + red[5] + red[6] + red[7];
    float mu = s * (1.0f / 1024.0f);
    float var = s2 * (1.0f / 1024.0f) - mu * mu;
    float rstd = rsqrtf(var + 1e-5f);
    float4 gv = *reinterpret_cast<const float4*>(g + tid * 4);
    float4 bv = *reinterpret_cast<const float4*>(bb + tid * 4);
    float4 o;
    o.x = (v.x - mu) * rstd * gv.x + bv.x;
    o.y = (v.y - mu) * rstd * gv.y + bv.y;
    o.z = (v.z - mu) * rstd * gv.z + bv.z;
    o.w = (v.w - mu) * rstd * gv.w + bv.w;
    *reinterpret_cast<float4*>(out + (size_t)row * D + tid * 4) = o;
}

extern "C" void kernel_launch(void* const* d_in, const int* in_sizes, int n_in,
                              void* d_out, int out_size, void* d_ws, size_t ws_size,
                              hipStream_t stream)
{
    const float* x    = (const float*)d_in[0];
    const float* qtl  = (const float*)d_in[1];
    const float* qimp = (const float*)d_in[2];
    const float* Wq = (const float*)d_in[3];
    const float* bq = (const float*)d_in[4];
    const float* Wk = (const float*)d_in[5];
    const float* bk = (const float*)d_in[6];
    const float* Wv = (const float*)d_in[7];
    const float* bv = (const float*)d_in[8];
    const float* Wo = (const float*)d_in[9];
    const float* bo = (const float*)d_in[10];
    const float* qpq_w1 = (const float*)d_in[11];
    const float* qpq_b1 = (const float*)d_in[12];
    const float* qpq_w2 = (const float*)d_in[13];
    const float* qpq_b2 = (const float*)d_in[14];
    const float* qpk_w1 = (const float*)d_in[15];
    const float* qpk_b1 = (const float*)d_in[16];
    const float* qpk_w2 = (const float*)d_in[17];
    const float* qpk_b2 = (const float*)d_in[18];
    const float* qpv_w1 = (const float*)d_in[19];
    const float* qpv_b1 = (const float*)d_in[20];
    const float* qpv_w2 = (const float*)d_in[21];
    const float* qpv_b2 = (const float*)d_in[22];
    const float* ln_g = (const float*)d_in[23];
    const float* ln_b = (const float*)d_in[24];
    (void)in_sizes; (void)n_in; (void)out_size; (void)ws_size;

    char* w = (char*)d_ws;
    float* xpe   = (float*)(w);                         // 16 MB fp32 residual
    u16* xpeb    = (u16*)(w + (16u << 20));             // 8 MB bf16
    u16* Wt      = (u16*)(w + (24u << 20));             // 8 MB: Wq,Wk,Wv,Wo transposed bf16
    u16* Qb      = (u16*)(w + (32u << 20));             // 8 MB bf16 [NR][D]
    u16* Kb      = (u16*)(w + (40u << 20));             // 8 MB bf16 [NR][D]
    u16* Vtb     = (u16*)(w + (48u << 20));             // 8 MB bf16 [B*NH*64][T]
    u16* AOb     = (u16*)(w + (56u << 20));             // 8 MB bf16 [NR][D]
    float* yb    = (float*)(w + (32u << 20));           // 16 MB fp32, aliases Qb/Kb (dead then)
    float* emb   = (float*)(w + (64u << 20));           // [3][B][D]
    float* scl   = (float*)(w + (64u << 20) + 32768);   // [B]
    float* part  = (float*)(w + (64u << 20) + 65536);   // [6][4][D]

    k_mlp1<<<dim3(4, 4, 6), 256, 0, stream>>>(qtl,
        qpq_w1, qpq_b1, qpq_w2,
        qpk_w1, qpk_b1, qpk_w2,
        qpv_w1, qpv_b1, qpv_w2,
        qimp, part, scl);
    k_mlp2<<<dim3(4, 6), 256, 0, stream>>>(part, qpq_b2, qpk_b2, qpv_b2, emb);
    k_prep<<<5120, 256, 0, stream>>>(x, xpe, xpeb, Wq, Wk, Wv, Wo, Wt);
    k_qkv<<<dim3(32, 8, 3), 256, 0, stream>>>(xpeb, Wt, bq, bk, bv, emb, scl, Qb, Kb, Vtb);
    k_attn<<<dim3(32, 16), 512, 0, stream>>>(Qb, Kb, Vtb, AOb);
    k_ogemm<<<dim3(32, 8), 256, 0, stream>>>(AOb, Wt + (size_t)3 * D * D, bo, xpe, yb);
    k_ln<<<4096, 256, 0, stream>>>(yb, ln_g, ln_b, (float*)d_out);
}